// Round 4
// baseline (353.785 us; speedup 1.0000x reference)
//
#include <hip/hip_runtime.h>
#include <math.h>

#define SEQ 2048
#define NHEAD 8
#define HDIM 64
#define BATCH 2

typedef __attribute__((ext_vector_type(8))) short short8;
typedef __attribute__((ext_vector_type(4))) float f32x4;

__device__ __forceinline__ ushort f2bf(float f) {
    union { float f; unsigned u; } v; v.f = f;
    unsigned r = v.u + 0x7FFFu + ((v.u >> 16) & 1u);   // RNE
    return (ushort)(r >> 16);
}

__device__ __forceinline__ f32x4 mfma16(short8 a, short8 b, f32x4 c) {
    return __builtin_amdgcn_mfma_f32_16x16x32_bf16(a, b, c, 0, 0, 0);
}

// ---------------- fused prep: pack x + transpose both weights ------------
__global__ __launch_bounds__(256)
void prep(const float* __restrict__ x, const float* __restrict__ w_qkv,
          const float* __restrict__ w_out, ushort* __restrict__ xb,
          ushort* __restrict__ wqkvT, ushort* __restrict__ woutT)
{
    __shared__ ushort tile[64][66];
    const int blk = blockIdx.x, t = threadIdx.x;
    if (blk < 1024) {                       // pack x -> bf16
        const int i = (blk * 256 + t) * 8;
        float4 a = *(const float4*)&x[i];
        float4 b = *(const float4*)&x[i + 4];
        union { ushort us[8]; uint4 v; } pk;
        pk.us[0] = f2bf(a.x); pk.us[1] = f2bf(a.y); pk.us[2] = f2bf(a.z); pk.us[3] = f2bf(a.w);
        pk.us[4] = f2bf(b.x); pk.us[5] = f2bf(b.y); pk.us[6] = f2bf(b.z); pk.us[7] = f2bf(b.w);
        *(uint4*)&xb[i] = pk.v;
        return;
    }
    const float* w; ushort* wT; int K, N, n0, k0;
    if (blk < 1216) { const int s = blk - 1024; w = w_qkv; wT = wqkvT; K = 512; N = 1536; n0 = (s % 24) * 64; k0 = (s / 24) * 64; }
    else            { const int s = blk - 1216; w = w_out; wT = woutT; K = 512; N = 512;  n0 = (s % 8) * 64;  k0 = (s / 8) * 64; }
#pragma unroll
    for (int i = 0; i < 4; ++i) {
        const int slot = t + i * 256;
        const int r = slot >> 4, c4 = (slot & 15) * 4;
        float4 v = *(const float4*)&w[(size_t)(k0 + r) * N + n0 + c4];
        tile[c4 + 0][r] = f2bf(v.x);
        tile[c4 + 1][r] = f2bf(v.y);
        tile[c4 + 2][r] = f2bf(v.z);
        tile[c4 + 3][r] = f2bf(v.w);
    }
    __syncthreads();
    const int n = t >> 2, kc = (t & 3) * 16;
    union { ushort us[16]; uint4 v[2]; } o;
#pragma unroll
    for (int j = 0; j < 16; ++j) o.us[j] = tile[n][kc + j];
    *(uint4*)&wT[(size_t)(n0 + n) * K + k0 + kc]     = o.v[0];
    *(uint4*)&wT[(size_t)(n0 + n) * K + k0 + kc + 8] = o.v[1];
}

// ---------------- QKV GEMM (64x128 tile) + RoPE epilogue, pipelined ------
__global__ __launch_bounds__(256)
void gemm_qkv_rope(const ushort* __restrict__ xb, const ushort* __restrict__ wT,
                   ushort* __restrict__ qb, ushort* __restrict__ kb,
                   ushort* __restrict__ vtb)
{
    __shared__ __align__(16) ushort As[64][72];
    __shared__ __align__(16) ushort Bs[128][72];
    const int t = threadIdx.x, lane = t & 63, w = t >> 6;
    const int quad = lane >> 4, l16 = lane & 15;
    const int m0 = blockIdx.y * 64, n0 = blockIdx.x * 128;
    const int mw = (w >> 1) * 32, nw = (w & 1) * 64;
    f32x4 acc[2][4] = {};

    const int ra = t >> 3, sg = (t & 7) * 8;           // As row / col-group
    uint4 ar[2], br[4];
#pragma unroll
    for (int i = 0; i < 2; ++i)
        ar[i] = *(const uint4*)&xb[(size_t)(m0 + ra + i * 32) * 512 + sg];
#pragma unroll
    for (int i = 0; i < 4; ++i)
        br[i] = *(const uint4*)&wT[(size_t)(n0 + ra + i * 32) * 512 + sg];

    for (int k0 = 0; k0 < 512; k0 += 64) {
#pragma unroll
        for (int i = 0; i < 2; ++i) *(uint4*)&As[ra + i * 32][sg] = ar[i];
#pragma unroll
        for (int i = 0; i < 4; ++i) *(uint4*)&Bs[ra + i * 32][sg] = br[i];
        __syncthreads();
        if (k0 < 448) {
#pragma unroll
            for (int i = 0; i < 2; ++i)
                ar[i] = *(const uint4*)&xb[(size_t)(m0 + ra + i * 32) * 512 + k0 + 64 + sg];
#pragma unroll
            for (int i = 0; i < 4; ++i)
                br[i] = *(const uint4*)&wT[(size_t)(n0 + ra + i * 32) * 512 + k0 + 64 + sg];
        }
#pragma unroll
        for (int ks = 0; ks < 2; ++ks) {
            short8 a[2], b[4];
#pragma unroll
            for (int i = 0; i < 2; ++i)
                a[i] = *(const short8*)&As[mw + i * 16 + l16][ks * 32 + quad * 8];
#pragma unroll
            for (int j = 0; j < 4; ++j)
                b[j] = *(const short8*)&Bs[nw + j * 16 + l16][ks * 32 + quad * 8];
#pragma unroll
            for (int i = 0; i < 2; ++i)
#pragma unroll
                for (int j = 0; j < 4; ++j)
                    acc[i][j] = mfma16(a[i], b[j], acc[i][j]);
        }
        __syncthreads();
    }

    const int sec = (n0 + nw) >> 9;   // 0=q 1=k 2=v, wave-uniform
    if (sec == 2) {
#pragma unroll
        for (int i = 0; i < 2; ++i) {
            const int m = m0 + mw + i * 16 + quad * 4;
            const int bidx = m >> 11, n = m & 2047;
#pragma unroll
            for (int j = 0; j < 4; ++j) {
                const int nc = n0 + nw + j * 16 + l16;
                const int d = nc & 63, h = (nc >> 6) & 7;
                ushort4 pk;
                pk.x = f2bf(acc[i][j][0]); pk.y = f2bf(acc[i][j][1]);
                pk.z = f2bf(acc[i][j][2]); pk.w = f2bf(acc[i][j][3]);
                *(ushort4*)&vtb[(((size_t)bidx * 8 + h) * 64 + d) * 2048 + n] = pk;
            }
        }
    } else {
        ushort* dst = (sec == 0) ? qb : kb;
        const float scale = (sec == 0) ? 0.125f : 1.0f;
#pragma unroll
        for (int j = 0; j < 4; ++j) {
            const int nc = n0 + nw + j * 16 + l16;
            const int d = nc & 63, h = (nc >> 6) & 7;
            const float inv = __expf(-(float)(d & ~1) * (9.2103403719761836f / 64.0f));
#pragma unroll
            for (int i = 0; i < 2; ++i)
#pragma unroll
            for (int r = 0; r < 4; ++r) {
                const int m = m0 + mw + i * 16 + quad * 4 + r;
                const int bidx = m >> 11, n = m & 2047;
                float sn, cs;
                __sincosf((float)n * inv, &sn, &cs);
                const float vacc = acc[i][j][r];
                const float partner = __shfl_xor(vacc, 1);
                const float rot = (d & 1) ? (vacc * cs + partner * sn)
                                          : (vacc * cs - partner * sn);
                dst[(((size_t)bidx * 8 + h) * 2048 + n) * 64 + d] = f2bf(rot * scale);
            }
        }
    }
}

// ---------------- flash attention, K-split x4, pipelined -----------------
__global__ __launch_bounds__(256)
void flash_attn_split(const ushort* __restrict__ qb, const ushort* __restrict__ kb,
                      const ushort* __restrict__ vtb, const float* __restrict__ bias,
                      float* __restrict__ opart, float* __restrict__ lsump)
{
    __shared__ __align__(16) ushort Ks[64][72];
    __shared__ __align__(16) ushort Vt[64][72];
    __shared__ __align__(16) ushort Ps[4][16][72];
    const int t = threadIdx.x, lane = t & 63, w = t >> 6;
    const int quad = lane >> 4, l16 = lane & 15;
    const int q0 = blockIdx.x * 64, h = blockIdx.y;
    const int b = blockIdx.z >> 2, split = blockIdx.z & 3;
    const int kbase = split * 512;
    const size_t bh = (size_t)(b * NHEAD + h);
    const ushort* Q  = qb  + bh * SEQ * HDIM;
    const ushort* K  = kb  + bh * SEQ * HDIM;
    const ushort* VT = vtb + bh * HDIM * SEQ;

    short8 qf[2];
    qf[0] = *(const short8*)&Q[(size_t)(q0 + w * 16 + l16) * HDIM + quad * 8];
    qf[1] = *(const short8*)&Q[(size_t)(q0 + w * 16 + l16) * HDIM + 32 + quad * 8];

    f32x4 oacc[4] = {};
    float lsum[4] = {};
    const float* bias_base = bias + ((size_t)h * SEQ + q0 + w * 16 + quad * 4) * SEQ;

    const int ra = t >> 3, sg = (t & 7) * 8;
    uint4 kr[2], vr[2];
#pragma unroll
    for (int i = 0; i < 2; ++i) {
        kr[i] = *(const uint4*)&K[(size_t)(kbase + ra + i * 32) * HDIM + sg];
        vr[i] = *(const uint4*)&VT[(size_t)(ra + i * 32) * SEQ + kbase + sg];
    }
    float bv[4][4];
#pragma unroll
    for (int r = 0; r < 4; ++r)
#pragma unroll
        for (int s = 0; s < 4; ++s)
            bv[r][s] = bias_base[(size_t)r * SEQ + kbase + s * 16 + l16];

#pragma unroll
    for (int it = 0; it < 8; ++it) {
        const int k0 = kbase + it * 64;
#pragma unroll
        for (int i = 0; i < 2; ++i) {
            *(uint4*)&Ks[ra + i * 32][sg] = kr[i];
            *(uint4*)&Vt[ra + i * 32][sg] = vr[i];
        }
        __syncthreads();

        float bvn[4][4];
        if (it < 7) {       // prefetch next tile: K,V, bias (in flight over MFMA)
#pragma unroll
            for (int i = 0; i < 2; ++i) {
                kr[i] = *(const uint4*)&K[(size_t)(k0 + 64 + ra + i * 32) * HDIM + sg];
                vr[i] = *(const uint4*)&VT[(size_t)(ra + i * 32) * SEQ + k0 + 64 + sg];
            }
#pragma unroll
            for (int r = 0; r < 4; ++r)
#pragma unroll
                for (int s = 0; s < 4; ++s)
                    bvn[r][s] = bias_base[(size_t)r * SEQ + k0 + 64 + s * 16 + l16];
        }

        // S = Q K^T
        f32x4 sacc[4] = {};
#pragma unroll
        for (int ks = 0; ks < 2; ++ks)
#pragma unroll
            for (int s = 0; s < 4; ++s) {
                short8 kf = *(const short8*)&Ks[s * 16 + l16][ks * 32 + quad * 8];
                sacc[s] = mfma16(qf[ks], kf, sacc[s]);
            }

        // p = exp(s + bias), row-sum deferred
#pragma unroll
        for (int r = 0; r < 4; ++r)
#pragma unroll
            for (int s = 0; s < 4; ++s) {
                const float p = __expf(sacc[s][r] + bv[r][s]);
                lsum[r] += p;
                Ps[w][quad * 4 + r][s * 16 + l16] = f2bf(p);
            }
        asm volatile("" ::: "memory");

        // O += P V
#pragma unroll
        for (int ks = 0; ks < 2; ++ks) {
            short8 pf = *(const short8*)&Ps[w][l16][ks * 32 + quad * 8];
#pragma unroll
            for (int s = 0; s < 4; ++s) {
                short8 vf = *(const short8*)&Vt[s * 16 + l16][ks * 32 + quad * 8];
                oacc[s] = mfma16(pf, vf, oacc[s]);
            }
        }
        __syncthreads();

        if (it < 7) {
#pragma unroll
            for (int r = 0; r < 4; ++r)
#pragma unroll
                for (int s = 0; s < 4; ++s) bv[r][s] = bvn[r][s];
        }
    }

    // partial epilogue: unnormalized O (fp32) + row sums
    const size_t pbase = ((size_t)bh * 4 + split) * SEQ;
#pragma unroll
    for (int r = 0; r < 4; ++r) {
        const int row = q0 + w * 16 + quad * 4 + r;
        float rs = lsum[r];
        rs += __shfl_xor(rs, 1, 16);
        rs += __shfl_xor(rs, 2, 16);
        rs += __shfl_xor(rs, 4, 16);
        rs += __shfl_xor(rs, 8, 16);
#pragma unroll
        for (int s = 0; s < 4; ++s)
            opart[(pbase + row) * 64 + s * 16 + l16] = oacc[s][r];
        if (l16 == 0) lsump[pbase + row] = rs;
    }
}

// ---------------- combine partials -> attnb bf16 [4096][512] -------------
__global__ __launch_bounds__(256)
void combine(const float* __restrict__ opart, const float* __restrict__ lsump,
             ushort* __restrict__ attnb)
{
    const int tid = blockIdx.x * 256 + threadIdx.x;
    const int d4 = (tid & 15) * 4;
    const int n  = (tid >> 4) & 2047;
    const int bh = tid >> 15;
    float ox = 0, oy = 0, oz = 0, ow = 0, L = 0;
#pragma unroll
    for (int s = 0; s < 4; ++s) {
        const size_t base = ((size_t)bh * 4 + s) * SEQ + n;
        float4 p = *(const float4*)&opart[base * 64 + d4];
        ox += p.x; oy += p.y; oz += p.z; ow += p.w;
        L += lsump[base];
    }
    const float inv = 1.0f / L;
    ushort4 pk;
    pk.x = f2bf(ox * inv); pk.y = f2bf(oy * inv);
    pk.z = f2bf(oz * inv); pk.w = f2bf(ow * inv);
    const int b = bh >> 3, h = bh & 7;
    *(ushort4*)&attnb[((size_t)b * SEQ + n) * 512 + h * 64 + d4] = pk;
}

// ---------------- out GEMM 64x64 tiles, pipelined ------------------------
__global__ __launch_bounds__(256)
void gemm_out(const ushort* __restrict__ Ab, const ushort* __restrict__ wT,
              float* __restrict__ C)
{
    __shared__ __align__(16) ushort As[64][72];
    __shared__ __align__(16) ushort Bs[64][72];
    const int t = threadIdx.x, lane = t & 63, w = t >> 6;
    const int quad = lane >> 4, l16 = lane & 15;
    const int m0 = blockIdx.y * 64, n0 = blockIdx.x * 64;
    const int mw = (w >> 1) * 32, nw = (w & 1) * 32;
    f32x4 acc[2][2] = {};

    const int ra = t >> 3, sg = (t & 7) * 8;
    uint4 ar[2], br[2];
#pragma unroll
    for (int i = 0; i < 2; ++i) {
        ar[i] = *(const uint4*)&Ab[(size_t)(m0 + ra + i * 32) * 512 + sg];
        br[i] = *(const uint4*)&wT[(size_t)(n0 + ra + i * 32) * 512 + sg];
    }

    for (int k0 = 0; k0 < 512; k0 += 64) {
#pragma unroll
        for (int i = 0; i < 2; ++i) {
            *(uint4*)&As[ra + i * 32][sg] = ar[i];
            *(uint4*)&Bs[ra + i * 32][sg] = br[i];
        }
        __syncthreads();
        if (k0 < 448) {
#pragma unroll
            for (int i = 0; i < 2; ++i) {
                ar[i] = *(const uint4*)&Ab[(size_t)(m0 + ra + i * 32) * 512 + k0 + 64 + sg];
                br[i] = *(const uint4*)&wT[(size_t)(n0 + ra + i * 32) * 512 + k0 + 64 + sg];
            }
        }
#pragma unroll
        for (int ks = 0; ks < 2; ++ks) {
            short8 a[2], b[2];
#pragma unroll
            for (int i = 0; i < 2; ++i)
                a[i] = *(const short8*)&As[mw + i * 16 + l16][ks * 32 + quad * 8];
#pragma unroll
            for (int j = 0; j < 2; ++j)
                b[j] = *(const short8*)&Bs[nw + j * 16 + l16][ks * 32 + quad * 8];
#pragma unroll
            for (int i = 0; i < 2; ++i)
#pragma unroll
                for (int j = 0; j < 2; ++j)
                    acc[i][j] = mfma16(a[i], b[j], acc[i][j]);
        }
        __syncthreads();
    }
#pragma unroll
    for (int i = 0; i < 2; ++i)
#pragma unroll
    for (int r = 0; r < 4; ++r) {
        const int m = m0 + mw + i * 16 + quad * 4 + r;
#pragma unroll
        for (int j = 0; j < 2; ++j)
            C[(size_t)m * 512 + n0 + nw + j * 16 + l16] = acc[i][j][r];
    }
}

extern "C" void kernel_launch(void* const* d_in, const int* in_sizes, int n_in,
                              void* d_out, int out_size, void* d_ws, size_t ws_size,
                              hipStream_t stream)
{
    const float* x        = (const float*)d_in[0];
    const float* pos_bias = (const float*)d_in[1];
    const float* w_qkv    = (const float*)d_in[2];
    const float* w_out    = (const float*)d_in[3];
    float* out = (float*)d_out;

    char* ws = (char*)d_ws;
    ushort* xb     = (ushort*)(ws);                            // 4 MB
    ushort* wqkvT  = (ushort*)(ws + 4194304);                  // 1.5 MB
    ushort* woutT  = (ushort*)(ws + 5767168);                  // 0.5 MB
    ushort* qb     = (ushort*)(ws + 6291456);                  // 4 MB
    ushort* kb     = (ushort*)(ws + 10485760);                 // 4 MB
    ushort* vtb    = (ushort*)(ws + 14680064);                 // 4 MB (V^T)
    ushort* attnb  = (ushort*)(ws + 18874368);                 // 4 MB
    float*  opart  = (float*) (ws + 23068672);                 // 33.5 MB
    float*  lsump  = (float*) (ws + 56623104);                 // 0.5 MB

    prep<<<1280, 256, 0, stream>>>(x, w_qkv, w_out, xb, wqkvT, woutT);
    gemm_qkv_rope<<<dim3(12, 64), 256, 0, stream>>>(xb, wqkvT, qb, kb, vtb);
    flash_attn_split<<<dim3(SEQ / 64, NHEAD, BATCH * 4), 256, 0, stream>>>(qb, kb, vtb, pos_bias, opart, lsump);
    combine<<<2048, 256, 0, stream>>>(opart, lsump, attnb);
    gemm_out<<<dim3(8, 64), 256, 0, stream>>>(attnb, woutT, out);
}

// Round 5
// 341.750 us; speedup vs baseline: 1.0352x; 1.0352x over previous
//
#include <hip/hip_runtime.h>
#include <math.h>

#define SEQ 2048
#define NHEAD 8
#define HDIM 64
#define BATCH 2

typedef __attribute__((ext_vector_type(8))) short short8;
typedef __attribute__((ext_vector_type(4))) float f32x4;

__device__ __forceinline__ ushort f2bf(float f) {
    union { float f; unsigned u; } v; v.f = f;
    unsigned r = v.u + 0x7FFFu + ((v.u >> 16) & 1u);   // RNE
    return (ushort)(r >> 16);
}

__device__ __forceinline__ f32x4 mfma16(short8 a, short8 b, f32x4 c) {
    return __builtin_amdgcn_mfma_f32_16x16x32_bf16(a, b, c, 0, 0, 0);
}

// ---------------- fused prep: pack x + transpose both weights ------------
__global__ __launch_bounds__(256)
void prep(const float* __restrict__ x, const float* __restrict__ w_qkv,
          const float* __restrict__ w_out, ushort* __restrict__ xb,
          ushort* __restrict__ wqkvT, ushort* __restrict__ woutT)
{
    __shared__ ushort tile[64][66];
    const int blk = blockIdx.x, t = threadIdx.x;
    if (blk < 1024) {                       // pack x -> bf16
        const int i = (blk * 256 + t) * 8;
        float4 a = *(const float4*)&x[i];
        float4 b = *(const float4*)&x[i + 4];
        union { ushort us[8]; uint4 v; } pk;
        pk.us[0] = f2bf(a.x); pk.us[1] = f2bf(a.y); pk.us[2] = f2bf(a.z); pk.us[3] = f2bf(a.w);
        pk.us[4] = f2bf(b.x); pk.us[5] = f2bf(b.y); pk.us[6] = f2bf(b.z); pk.us[7] = f2bf(b.w);
        *(uint4*)&xb[i] = pk.v;
        return;
    }
    const float* w; ushort* wT; int K, N, n0, k0;
    if (blk < 1216) { const int s = blk - 1024; w = w_qkv; wT = wqkvT; K = 512; N = 1536; n0 = (s % 24) * 64; k0 = (s / 24) * 64; }
    else            { const int s = blk - 1216; w = w_out; wT = woutT; K = 512; N = 512;  n0 = (s % 8) * 64;  k0 = (s / 8) * 64; }
#pragma unroll
    for (int i = 0; i < 4; ++i) {
        const int slot = t + i * 256;
        const int r = slot >> 4, c4 = (slot & 15) * 4;
        float4 v = *(const float4*)&w[(size_t)(k0 + r) * N + n0 + c4];
        tile[c4 + 0][r] = f2bf(v.x);
        tile[c4 + 1][r] = f2bf(v.y);
        tile[c4 + 2][r] = f2bf(v.z);
        tile[c4 + 3][r] = f2bf(v.w);
    }
    __syncthreads();
    const int n = t >> 2, kc = (t & 3) * 16;
    union { ushort us[16]; uint4 v[2]; } o;
#pragma unroll
    for (int j = 0; j < 16; ++j) o.us[j] = tile[n][kc + j];
    *(uint4*)&wT[(size_t)(n0 + n) * K + k0 + kc]     = o.v[0];
    *(uint4*)&wT[(size_t)(n0 + n) * K + k0 + kc + 8] = o.v[1];
}

// ---------------- QKV GEMM (64x128 tile) + RoPE epilogue, pipelined ------
__global__ __launch_bounds__(256)
void gemm_qkv_rope(const ushort* __restrict__ xb, const ushort* __restrict__ wT,
                   ushort* __restrict__ qb, ushort* __restrict__ kb,
                   ushort* __restrict__ vtb)
{
    __shared__ __align__(16) ushort As[64][72];
    __shared__ __align__(16) ushort Bs[128][72];
    const int t = threadIdx.x, lane = t & 63, w = t >> 6;
    const int quad = lane >> 4, l16 = lane & 15;
    const int m0 = blockIdx.y * 64, n0 = blockIdx.x * 128;
    const int mw = (w >> 1) * 32, nw = (w & 1) * 64;
    f32x4 acc[2][4] = {};

    const int ra = t >> 3, sg = (t & 7) * 8;
    uint4 ar[2], br[4];
#pragma unroll
    for (int i = 0; i < 2; ++i)
        ar[i] = *(const uint4*)&xb[(size_t)(m0 + ra + i * 32) * 512 + sg];
#pragma unroll
    for (int i = 0; i < 4; ++i)
        br[i] = *(const uint4*)&wT[(size_t)(n0 + ra + i * 32) * 512 + sg];

    for (int k0 = 0; k0 < 512; k0 += 64) {
#pragma unroll
        for (int i = 0; i < 2; ++i) *(uint4*)&As[ra + i * 32][sg] = ar[i];
#pragma unroll
        for (int i = 0; i < 4; ++i) *(uint4*)&Bs[ra + i * 32][sg] = br[i];
        __syncthreads();
        if (k0 < 448) {
#pragma unroll
            for (int i = 0; i < 2; ++i)
                ar[i] = *(const uint4*)&xb[(size_t)(m0 + ra + i * 32) * 512 + k0 + 64 + sg];
#pragma unroll
            for (int i = 0; i < 4; ++i)
                br[i] = *(const uint4*)&wT[(size_t)(n0 + ra + i * 32) * 512 + k0 + 64 + sg];
        }
#pragma unroll
        for (int ks = 0; ks < 2; ++ks) {
            short8 a[2], b[4];
#pragma unroll
            for (int i = 0; i < 2; ++i)
                a[i] = *(const short8*)&As[mw + i * 16 + l16][ks * 32 + quad * 8];
#pragma unroll
            for (int j = 0; j < 4; ++j)
                b[j] = *(const short8*)&Bs[nw + j * 16 + l16][ks * 32 + quad * 8];
#pragma unroll
            for (int i = 0; i < 2; ++i)
#pragma unroll
                for (int j = 0; j < 4; ++j)
                    acc[i][j] = mfma16(a[i], b[j], acc[i][j]);
        }
        __syncthreads();
    }

    const int sec = (n0 + nw) >> 9;   // 0=q 1=k 2=v, wave-uniform
    if (sec == 2) {
#pragma unroll
        for (int i = 0; i < 2; ++i) {
            const int m = m0 + mw + i * 16 + quad * 4;
            const int bidx = m >> 11, n = m & 2047;
#pragma unroll
            for (int j = 0; j < 4; ++j) {
                const int nc = n0 + nw + j * 16 + l16;
                const int d = nc & 63, h = (nc >> 6) & 7;
                ushort4 pk;
                pk.x = f2bf(acc[i][j][0]); pk.y = f2bf(acc[i][j][1]);
                pk.z = f2bf(acc[i][j][2]); pk.w = f2bf(acc[i][j][3]);
                *(ushort4*)&vtb[(((size_t)bidx * 8 + h) * 64 + d) * 2048 + n] = pk;
            }
        }
    } else {
        ushort* dst = (sec == 0) ? qb : kb;
        const float scale = (sec == 0) ? 0.125f : 1.0f;
#pragma unroll
        for (int j = 0; j < 4; ++j) {
            const int nc = n0 + nw + j * 16 + l16;
            const int d = nc & 63, h = (nc >> 6) & 7;
            const float inv = __expf(-(float)(d & ~1) * (9.2103403719761836f / 64.0f));
#pragma unroll
            for (int i = 0; i < 2; ++i)
#pragma unroll
            for (int r = 0; r < 4; ++r) {
                const int m = m0 + mw + i * 16 + quad * 4 + r;
                const int bidx = m >> 11, n = m & 2047;
                float sn, cs;
                __sincosf((float)n * inv, &sn, &cs);
                const float vacc = acc[i][j][r];
                const float partner = __shfl_xor(vacc, 1);
                const float rot = (d & 1) ? (vacc * cs + partner * sn)
                                          : (vacc * cs - partner * sn);
                dst[(((size_t)bidx * 8 + h) * 2048 + n) * 64 + d] = f2bf(rot * scale);
            }
        }
    }
}

// ---------------- flash attention: dbuf K/V LDS, 1 barrier/iter ----------
__global__ __launch_bounds__(256)
void flash_attn_mfma(const ushort* __restrict__ qb, const ushort* __restrict__ kb,
                     const ushort* __restrict__ vtb, const float* __restrict__ bias,
                     ushort* __restrict__ ob)
{
    __shared__ __align__(16) ushort Ks[2][64][72];
    __shared__ __align__(16) ushort Vt[2][64][72];
    __shared__ __align__(16) ushort Ps[4][16][88];
    const int t = threadIdx.x, lane = t & 63, w = t >> 6;
    const int quad = lane >> 4, l16 = lane & 15;
    const int q0 = blockIdx.x * 64, h = blockIdx.y, b = blockIdx.z;
    const size_t bh = (size_t)(b * NHEAD + h);
    const ushort* Q  = qb  + bh * SEQ * HDIM;
    const ushort* K  = kb  + bh * SEQ * HDIM;
    const ushort* VT = vtb + bh * HDIM * SEQ;

    short8 qf[2];
    qf[0] = *(const short8*)&Q[(size_t)(q0 + w * 16 + l16) * HDIM + quad * 8];
    qf[1] = *(const short8*)&Q[(size_t)(q0 + w * 16 + l16) * HDIM + 32 + quad * 8];

    f32x4 oacc[4] = {};
    float lsum[4] = {};
    const float* bias_base = bias + ((size_t)h * SEQ + q0 + w * 16 + quad * 4) * SEQ;

    const int ra = t >> 3, sg = (t & 7) * 8;
    uint4 kr[2], vr[2];
    // K/V loads first, bias second: ds_write's vmcnt wait leaves bias in flight
#pragma unroll
    for (int i = 0; i < 2; ++i) {
        kr[i] = *(const uint4*)&K[(size_t)(ra + i * 32) * HDIM + sg];
        vr[i] = *(const uint4*)&VT[(size_t)(ra + i * 32) * SEQ + sg];
    }
    float bv[2][4][4];
#pragma unroll
    for (int p = 0; p < 2; ++p)
#pragma unroll
        for (int r = 0; r < 4; ++r)
#pragma unroll
            for (int s = 0; s < 4; ++s)
                bv[p][r][s] = bias_base[(size_t)r * SEQ + p * 64 + s * 16 + l16];
#pragma unroll
    for (int i = 0; i < 2; ++i) {
        *(uint4*)&Ks[0][ra + i * 32][sg] = kr[i];
        *(uint4*)&Vt[0][ra + i * 32][sg] = vr[i];
    }
    __syncthreads();

#pragma unroll 2
    for (int it = 0; it < 32; ++it) {
        const int cur = it & 1;
        const int k0 = it * 64;
        // prefetch next K/V tile (lands during this iter's compute)
        if (it < 31) {
#pragma unroll
            for (int i = 0; i < 2; ++i) {
                kr[i] = *(const uint4*)&K[(size_t)(k0 + 64 + ra + i * 32) * HDIM + sg];
                vr[i] = *(const uint4*)&VT[(size_t)(ra + i * 32) * SEQ + k0 + 64 + sg];
            }
        }

        // S = Q K^T
        f32x4 sacc[4] = {};
#pragma unroll
        for (int ks = 0; ks < 2; ++ks)
#pragma unroll
            for (int s = 0; s < 4; ++s) {
                short8 kf = *(const short8*)&Ks[cur][s * 16 + l16][ks * 32 + quad * 8];
                sacc[s] = mfma16(qf[ks], kf, sacc[s]);
            }

        // p = exp(s + bias); row-sum deferred to epilogue
#pragma unroll
        for (int r = 0; r < 4; ++r)
#pragma unroll
            for (int s = 0; s < 4; ++s) {
                const float p = __expf(sacc[s][r] + bv[cur][r][s]);
                lsum[r] += p;
                Ps[w][quad * 4 + r][s * 16 + l16] = f2bf(p);
            }
        // bias slot freed: prefetch bias for it+2 (~1.5 iters of cover)
        if (it < 30) {
#pragma unroll
            for (int r = 0; r < 4; ++r)
#pragma unroll
                for (int s = 0; s < 4; ++s)
                    bv[cur][r][s] = bias_base[(size_t)r * SEQ + k0 + 128 + s * 16 + l16];
        }
        asm volatile("" ::: "memory");   // per-wave Ps: order writes before reads

        // O += P V
#pragma unroll
        for (int ks = 0; ks < 2; ++ks) {
            short8 pf = *(const short8*)&Ps[w][l16][ks * 32 + quad * 8];
#pragma unroll
            for (int s = 0; s < 4; ++s) {
                short8 vf = *(const short8*)&Vt[cur][s * 16 + l16][ks * 32 + quad * 8];
                oacc[s] = mfma16(pf, vf, oacc[s]);
            }
        }

        // stage next tile into alternate buffer; single barrier per iter
        if (it < 31) {
#pragma unroll
            for (int i = 0; i < 2; ++i) {
                *(uint4*)&Ks[cur ^ 1][ra + i * 32][sg] = kr[i];
                *(uint4*)&Vt[cur ^ 1][ra + i * 32][sg] = vr[i];
            }
        }
        __syncthreads();
    }

    // epilogue: cross-lane row-sum, normalize, write [4096][512]
#pragma unroll
    for (int r = 0; r < 4; ++r) {
        float rs = lsum[r];
        rs += __shfl_xor(rs, 1, 16);
        rs += __shfl_xor(rs, 2, 16);
        rs += __shfl_xor(rs, 4, 16);
        rs += __shfl_xor(rs, 8, 16);
        const float invl = 1.0f / rs;
        const size_t m = (size_t)b * SEQ + q0 + w * 16 + quad * 4 + r;
#pragma unroll
        for (int s = 0; s < 4; ++s)
            ob[m * 512 + h * HDIM + s * 16 + l16] = f2bf(oacc[s][r] * invl);
    }
}

// ---------------- out GEMM 64x64 tiles, pipelined ------------------------
__global__ __launch_bounds__(256)
void gemm_out(const ushort* __restrict__ Ab, const ushort* __restrict__ wT,
              float* __restrict__ C)
{
    __shared__ __align__(16) ushort As[64][72];
    __shared__ __align__(16) ushort Bs[64][72];
    const int t = threadIdx.x, lane = t & 63, w = t >> 6;
    const int quad = lane >> 4, l16 = lane & 15;
    const int m0 = blockIdx.y * 64, n0 = blockIdx.x * 64;
    const int mw = (w >> 1) * 32, nw = (w & 1) * 32;
    f32x4 acc[2][2] = {};

    const int ra = t >> 3, sg = (t & 7) * 8;
    uint4 ar[2], br[2];
#pragma unroll
    for (int i = 0; i < 2; ++i) {
        ar[i] = *(const uint4*)&Ab[(size_t)(m0 + ra + i * 32) * 512 + sg];
        br[i] = *(const uint4*)&wT[(size_t)(n0 + ra + i * 32) * 512 + sg];
    }

    for (int k0 = 0; k0 < 512; k0 += 64) {
#pragma unroll
        for (int i = 0; i < 2; ++i) {
            *(uint4*)&As[ra + i * 32][sg] = ar[i];
            *(uint4*)&Bs[ra + i * 32][sg] = br[i];
        }
        __syncthreads();
        if (k0 < 448) {
#pragma unroll
            for (int i = 0; i < 2; ++i) {
                ar[i] = *(const uint4*)&Ab[(size_t)(m0 + ra + i * 32) * 512 + k0 + 64 + sg];
                br[i] = *(const uint4*)&wT[(size_t)(n0 + ra + i * 32) * 512 + k0 + 64 + sg];
            }
        }
#pragma unroll
        for (int ks = 0; ks < 2; ++ks) {
            short8 a[2], b[2];
#pragma unroll
            for (int i = 0; i < 2; ++i)
                a[i] = *(const short8*)&As[mw + i * 16 + l16][ks * 32 + quad * 8];
#pragma unroll
            for (int j = 0; j < 2; ++j)
                b[j] = *(const short8*)&Bs[nw + j * 16 + l16][ks * 32 + quad * 8];
#pragma unroll
            for (int i = 0; i < 2; ++i)
#pragma unroll
                for (int j = 0; j < 2; ++j)
                    acc[i][j] = mfma16(a[i], b[j], acc[i][j]);
        }
        __syncthreads();
    }
#pragma unroll
    for (int i = 0; i < 2; ++i)
#pragma unroll
    for (int r = 0; r < 4; ++r) {
        const int m = m0 + mw + i * 16 + quad * 4 + r;
#pragma unroll
        for (int j = 0; j < 2; ++j)
            C[(size_t)m * 512 + n0 + nw + j * 16 + l16] = acc[i][j][r];
    }
}

extern "C" void kernel_launch(void* const* d_in, const int* in_sizes, int n_in,
                              void* d_out, int out_size, void* d_ws, size_t ws_size,
                              hipStream_t stream)
{
    const float* x        = (const float*)d_in[0];
    const float* pos_bias = (const float*)d_in[1];
    const float* w_qkv    = (const float*)d_in[2];
    const float* w_out    = (const float*)d_in[3];
    float* out = (float*)d_out;

    char* ws = (char*)d_ws;
    ushort* xb     = (ushort*)(ws);                            // 4 MB
    ushort* wqkvT  = (ushort*)(ws + 4194304);                  // 1.5 MB
    ushort* woutT  = (ushort*)(ws + 5767168);                  // 0.5 MB
    ushort* qb     = (ushort*)(ws + 6291456);                  // 4 MB
    ushort* kb     = (ushort*)(ws + 10485760);                 // 4 MB
    ushort* vtb    = (ushort*)(ws + 14680064);                 // 4 MB (V^T)
    ushort* attnb  = (ushort*)(ws + 18874368);                 // 4 MB

    prep<<<1280, 256, 0, stream>>>(x, w_qkv, w_out, xb, wqkvT, woutT);
    gemm_qkv_rope<<<dim3(12, 64), 256, 0, stream>>>(xb, wqkvT, qb, kb, vtb);
    flash_attn_mfma<<<dim3(SEQ / 64, NHEAD, BATCH), 256, 0, stream>>>(qb, kb, vtb, pos_bias, attnb);
    gemm_out<<<dim3(8, 64), 256, 0, stream>>>(attnb, woutT, out);
}